// Round 11
// baseline (3699.389 us; speedup 1.0000x reference)
//
#include <hip/hip_runtime.h>
#include <hip/hip_bf16.h>

#define Bsz 256
#define Nd  512
#define Hd  2048
#define Td  64
#define OFF_T (Bsz * Td * Nd)
#define OFF_L (OFF_T + Td)
#define LDU 514   // Ulds stride (elements)
#define LDZ 136   // Zlds stride

typedef __attribute__((ext_vector_type(8))) short short8;
typedef __attribute__((ext_vector_type(4))) float f32x4;

static __device__ __forceinline__ unsigned short f2bf(float x) {
  unsigned u = __builtin_bit_cast(unsigned, x);
  u += 0x7FFFu + ((u >> 16) & 1u);   // RNE
  return (unsigned short)(u >> 16);
}
static __device__ __forceinline__ float fast_tanh(float x) {
  float ex = __expf(2.0f * x);       // inf-safe
  return 1.0f - 2.0f / (ex + 1.0f);
}
// ---- agent-scope (sc1, LLC coherence point) primitives — the ONLY verified
// cross-block path on this part (live & correct rounds 3-6, 9, 10).
static __device__ __forceinline__ unsigned long long lda64(const void* p) {
  return __hip_atomic_load((const unsigned long long*)p, __ATOMIC_RELAXED,
                           __HIP_MEMORY_SCOPE_AGENT);
}
static __device__ __forceinline__ void sta64(void* p, unsigned long long v) {
  __hip_atomic_store((unsigned long long*)p, v, __ATOMIC_RELAXED,
                     __HIP_MEMORY_SCOPE_AGENT);
}
static __device__ __forceinline__ unsigned lda32(const unsigned* p) {
  return __hip_atomic_load(p, __ATOMIC_RELAXED, __HIP_MEMORY_SCOPE_AGENT);
}
static __device__ __forceinline__ void sta32(unsigned* p, unsigned v) {
  __hip_atomic_store(p, v, __ATOMIC_RELAXED, __HIP_MEMORY_SCOPE_AGENT);
}
// wave-local store drain: all this wave's global stores ACKed at LLC.
// "memory" clobber keeps the following seq-posts ordered after it.
static __device__ __forceinline__ void wave_drain() {
  asm volatile("s_waitcnt vmcnt(0)" ::: "memory");
}

// 256 blocks x 256 threads (4 waves), 1 block/CU (LDS-forced).
// pod g = blk & 15 (16 blocks sharing batch rows g*16..g*16+15);
// il = blk >> 4: H-slice owner (GEMM1) / N-slice owner (GEMM2).
// Sync = per-(member,row) seqlock records: per-wave drain + seq post,
// per-thread seq-then-data consume. No block-wide rendezvous.
__launch_bounds__(256, 1)
__global__ void ode_sq(const float* __restrict__ y0g, const float* __restrict__ te,
                       const float* __restrict__ W1, const float* __restrict__ b1,
                       const float* __restrict__ W2, const float* __restrict__ b2,
                       float* __restrict__ out, unsigned* __restrict__ seqK,
                       unsigned* __restrict__ seqZ,
                       float* __restrict__ kD, unsigned short* __restrict__ ZD) {
  __shared__ unsigned short Ulds[16 * LDU];
  __shared__ unsigned short Zlds[16 * LDZ];
  __shared__ float red[4][16][33];
  __shared__ char spad[56 * 1024];   // occupancy limiter: 1 block/CU

  const int blk = blockIdx.x;
  const int g = blk & 15, il = blk >> 4;
  const int tid = threadIdx.x;
  const int wv = tid >> 6, lane = tid & 63;
  const int lr = lane & 15, lk = lane >> 4;

  if (te[0] == 1.0e30f) {            // never true; keeps spad allocated
    ((volatile char*)spad)[tid] = (char)tid;
    out[0] = ((volatile char*)spad)[0];
  }

  // ---------- one-time: resident weight fragments ----------
  short8 w1f[2][16];                 // W1 slice: cols il*128 + wv*32 + n*16 + lr
  {
    const int hbase = il * 128 + wv * 32;
    #pragma unroll
    for (int n = 0; n < 2; ++n) {
      const int col = hbase + n * 16 + lr;
      #pragma unroll
      for (int kt = 0; kt < 16; ++kt) {
        short8 v;
        #pragma unroll
        for (int jj = 0; jj < 8; ++jj)
          v[jj] = (short)f2bf(W1[(kt * 32 + lk * 8 + jj) * Hd + col]);
        w1f[n][kt] = v;
      }
    }
  }
  short8 w2f[2][16];                 // W2 slice: cols il*32 + n*16 + lr, K-chunk wv*512
  {
    #pragma unroll
    for (int n = 0; n < 2; ++n) {
      const int col = il * 32 + n * 16 + lr;
      #pragma unroll
      for (int kt = 0; kt < 16; ++kt) {
        short8 v;
        #pragma unroll
        for (int jj = 0; jj < 8; ++jj)
          v[jj] = (short)f2bf(W2[(wv * 512 + kt * 32 + lk * 8 + jj) * Nd + col]);
        w2f[n][kt] = v;
      }
    }
  }
  float b1c[2];
  b1c[0] = b1[il * 128 + wv * 32 + lr];
  b1c[1] = b1[il * 128 + wv * 32 + 16 + lr];

  // ---------- per-thread state mapping ----------
  const int r  = tid >> 4;           // local m-row 0..15 (wave r>>2)
  const int cq = tid & 15;           // 32-col N chunk owner = member cq
  const int cb = cq * 32;
  const int rowg = g * 16 + r;
  const int c2 = (tid & 15) * 2;
  const int rowe = tid >> 4;
  const float b2e0 = b2[il * 32 + c2], b2e1 = b2[il * 32 + c2 + 1];

  // record index helpers
  const int podbase = g * 16;                       // member-major within pod
  unsigned* mySeqK = &seqK[(podbase + cq) * 16 + r];        // record I consume (kv)
  const float* myKD = &kD[((podbase + cq) * 16 + r) * 32];  // its 128B of data

  float yv[32];
  #pragma unroll
  for (int gg = 0; gg < 8; ++gg) {
    f32x4 v = *(const f32x4*)&y0g[rowg * Nd + cb + gg * 4];
    yv[gg * 4 + 0] = v[0]; yv[gg * 4 + 1] = v[1];
    yv[gg * 4 + 2] = v[2]; yv[gg * 4 + 3] = v[3];
  }
  float acc_y[32];
  #pragma unroll
  for (int p = 0; p < 32; ++p) acc_y[p] = 0.0f;

  // ---------- pre-loop outputs ----------
  if (cq == il) {
    #pragma unroll
    for (int gg = 0; gg < 8; ++gg) {
      f32x4 v = {yv[gg * 4], yv[gg * 4 + 1], yv[gg * 4 + 2], yv[gg * 4 + 3]};
      *(f32x4*)&out[rowg * (Td * Nd) + cb + gg * 4] = v;
    }
  }
  if (blk == 0) {
    if (tid < Td) out[OFF_T + tid] = te[tid];
    out[OFF_L + tid] = 0.0f;
  }

  // ---------- main loop: 63 steps x 4 evals ----------
  int j = 0;
  for (int t = 0; t < Td - 1; ++t) {
    const float h = te[t + 1] - te[t];
    for (int e = 1; e <= 4; ++e) {
      // ---- consume k(j-1): per-thread seq-then-data (record (cq, r)) ----
      float kv[32];
      if (!(e == 1 && t == 0)) {
        const unsigned tgt = (unsigned)j;     // k of eval j-1 carries seq j
        while (!__all((int)(lda32(mySeqK) >= tgt)))
          __builtin_amdgcn_s_sleep(1);
        #pragma unroll
        for (int p2 = 0; p2 < 16; ++p2) {
          unsigned long long q = lda64(myKD + p2 * 2);
          kv[2 * p2 + 0] = __builtin_bit_cast(float, (unsigned)(q & 0xFFFFFFFFull));
          kv[2 * p2 + 1] = __builtin_bit_cast(float, (unsigned)(q >> 32));
        }
      }
      // ---- U phase ----
      if (e == 1) {
        if (t > 0) {
          const float hp6 = (te[t] - te[t - 1]) * (1.0f / 6.0f);
          #pragma unroll
          for (int p2 = 0; p2 < 32; ++p2) yv[p2] += hp6 * (acc_y[p2] + kv[p2]);
          if (cq == il) {
            #pragma unroll
            for (int gg = 0; gg < 8; ++gg) {
              f32x4 v = {yv[gg * 4], yv[gg * 4 + 1], yv[gg * 4 + 2], yv[gg * 4 + 3]};
              *(f32x4*)&out[rowg * (Td * Nd) + t * Nd + cb + gg * 4] = v;
            }
          }
        }
        #pragma unroll
        for (int p2 = 0; p2 < 32; ++p2) acc_y[p2] = 0.0f;
        #pragma unroll
        for (int gg = 0; gg < 4; ++gg) {
          short8 s;
          #pragma unroll
          for (int p2 = 0; p2 < 8; ++p2) s[p2] = (short)f2bf(yv[gg * 8 + p2]);
          *(short8*)&Ulds[r * LDU + cb + gg * 8] = s;
        }
      } else {
        const float c = (e == 4) ? h : 0.5f * h;
        const float w = (e == 2) ? 1.0f : 2.0f;
        #pragma unroll
        for (int gg = 0; gg < 4; ++gg) {
          short8 s;
          #pragma unroll
          for (int p2 = 0; p2 < 8; ++p2) {
            const int idx = gg * 8 + p2;
            acc_y[idx] += w * kv[idx];
            s[p2] = (short)f2bf(yv[idx] + c * kv[idx]);
          }
          *(short8*)&Ulds[r * LDU + cb + gg * 8] = s;
        }
      }
      __syncthreads();                              // barrier 1: U complete

      // ---- GEMM1: [16,512] @ W1-slice ----
      f32x4 acc1_0 = {0.f, 0.f, 0.f, 0.f}, acc1_1 = {0.f, 0.f, 0.f, 0.f};
      {
        const int abase = lr * LDU + lk * 8;
        #pragma unroll
        for (int kt = 0; kt < 16; ++kt) {
          short8 a = *(const short8*)&Ulds[abase + kt * 32];
          acc1_0 = __builtin_amdgcn_mfma_f32_16x16x32_bf16(a, w1f[0][kt], acc1_0, 0, 0, 0);
          acc1_1 = __builtin_amdgcn_mfma_f32_16x16x32_bf16(a, w1f[1][kt], acc1_1, 0, 0, 0);
        }
      }
      #pragma unroll
      for (int n = 0; n < 2; ++n) {
        f32x4 a = n ? acc1_1 : acc1_0;
        #pragma unroll
        for (int q = 0; q < 4; ++q)
          Zlds[(lk * 4 + q) * LDZ + wv * 32 + n * 16 + lr] = f2bf(fast_tanh(a[q] + b1c[n]));
      }
      __syncthreads();                              // barrier 2: Zlds complete

      // ---- export Z records (member-local 128-col layout) + per-wave post ----
      {
        int zr0 = tid >> 5, zc4 = tid & 31;         // u=0: rows 0..7
        unsigned long long v0 = *(const unsigned long long*)&Zlds[zr0 * LDZ + zc4 * 4];
        sta64(&ZD[((podbase + il) * 16 + zr0) * 128 + zc4 * 4], v0);
        int zr1 = 8 + zr0;                          // u=1: rows 8..15
        unsigned long long v1 = *(const unsigned long long*)&Zlds[zr1 * LDZ + zc4 * 4];
        sta64(&ZD[((podbase + il) * 16 + zr1) * 128 + zc4 * 4], v1);
        wave_drain();                               // this wave's Z at LLC
        if ((tid & 31) == 0) {                      // 2 lanes/wave post 4 rows
          sta32(&seqZ[(podbase + il) * 16 + zr0], (unsigned)(j + 1));
          sta32(&seqZ[(podbase + il) * 16 + zr1], (unsigned)(j + 1));
        }
      }

      // ---- GEMM2: per-member seq-gated pipeline (wave wv: members wv*4+q) ----
      f32x4 acc2_0 = {0.f, 0.f, 0.f, 0.f}, acc2_1 = {0.f, 0.f, 0.f, 0.f};
      {
        const unsigned zt = (unsigned)(j + 1);
        #pragma unroll
        for (int q = 0; q < 4; ++q) {
          const int m = wv * 4 + q;
          const unsigned* sp = &seqZ[(podbase + m) * 16 + lr];   // 1 line/member
          while (!__all((int)(lda32(sp) >= zt)))
            __builtin_amdgcn_s_sleep(1);
          const unsigned short* zp = &ZD[((podbase + m) * 16 + lr) * 128 + lk * 8];
          #pragma unroll
          for (int k2 = 0; k2 < 4; ++k2) {
            union { unsigned long long q2[2]; short8 s; } az_;
            az_.q2[0] = lda64(zp + k2 * 32);
            az_.q2[1] = lda64(zp + k2 * 32 + 4);
            const int kt = q * 4 + k2;
            acc2_0 = __builtin_amdgcn_mfma_f32_16x16x32_bf16(az_.s, w2f[0][kt], acc2_0, 0, 0, 0);
            acc2_1 = __builtin_amdgcn_mfma_f32_16x16x32_bf16(az_.s, w2f[1][kt], acc2_1, 0, 0, 0);
          }
        }
      }
      // ---- deterministic cross-wave reduce ----
      #pragma unroll
      for (int q = 0; q < 4; ++q) {
        red[wv][lk * 4 + q][lr]      = acc2_0[q];
        red[wv][lk * 4 + q][16 + lr] = acc2_1[q];
      }
      __syncthreads();                              // barrier 3: partials in LDS
      {
        float s0 = red[0][rowe][c2] + red[1][rowe][c2] + red[2][rowe][c2] + red[3][rowe][c2] + b2e0;
        float s1 = red[0][rowe][c2 + 1] + red[1][rowe][c2 + 1] + red[2][rowe][c2 + 1] + red[3][rowe][c2 + 1] + b2e1;
        unsigned long long pk =
            ((unsigned long long)__builtin_bit_cast(unsigned, s1) << 32) |
            __builtin_bit_cast(unsigned, s0);
        sta64(&kD[((podbase + il) * 16 + rowe) * 32 + c2], pk);
        wave_drain();                               // this wave's 4 rows at LLC
        if ((tid & 15) == 0)                        // 4 lanes/wave post rows
          sta32(&seqK[(podbase + il) * 16 + rowe], (unsigned)(j + 1));
      }
      ++j;
    }
  }

  // ---------- epilogue: final y-update + y_t[:, 63, :] ----------
  {
    const unsigned tgt = (unsigned)j;               // j == 252
    while (!__all((int)(lda32(mySeqK) >= tgt)))
      __builtin_amdgcn_s_sleep(1);
    float kv[32];
    #pragma unroll
    for (int p2 = 0; p2 < 16; ++p2) {
      unsigned long long q = lda64(myKD + p2 * 2);
      kv[2 * p2 + 0] = __builtin_bit_cast(float, (unsigned)(q & 0xFFFFFFFFull));
      kv[2 * p2 + 1] = __builtin_bit_cast(float, (unsigned)(q >> 32));
    }
    const float hp6 = (te[Td - 1] - te[Td - 2]) * (1.0f / 6.0f);
    #pragma unroll
    for (int p2 = 0; p2 < 32; ++p2) yv[p2] += hp6 * (acc_y[p2] + kv[p2]);
    if (cq == il) {
      #pragma unroll
      for (int gg = 0; gg < 8; ++gg) {
        f32x4 v = {yv[gg * 4], yv[gg * 4 + 1], yv[gg * 4 + 2], yv[gg * 4 + 3]};
        *(f32x4*)&out[rowg * (Td * Nd) + (Td - 1) * Nd + cb + gg * 4] = v;
      }
    }
  }
}

extern "C" void kernel_launch(void* const* d_in, const int* in_sizes, int n_in,
                              void* d_out, int out_size, void* d_ws, size_t ws_size,
                              hipStream_t stream) {
  const float* y0 = (const float*)d_in[0];
  const float* te = (const float*)d_in[1];
  const float* W1 = (const float*)d_in[2];
  const float* b1 = (const float*)d_in[3];
  const float* W2 = (const float*)d_in[4];
  const float* b2 = (const float*)d_in[5];
  float* out = (float*)d_out;

  char* p = (char*)d_ws;
  unsigned* seqK = (unsigned*)p;                        // 16KB: [pod][member][row]
  unsigned* seqZ = (unsigned*)(p + 16 * 1024);          // 16KB
  float* kD = (float*)(p + 32 * 1024);                  // 512KB: [pod][member][row][32]
  unsigned short* ZD = (unsigned short*)(p + 32 * 1024 + 512 * 1024);  // 1MB: [pod][member][row][128]

  hipMemsetAsync(d_ws, 0, 32 * 1024, stream);           // zero seq arrays
  ode_sq<<<dim3(256), dim3(256), 0, stream>>>(y0, te, W1, b1, W2, b2, out,
                                              seqK, seqZ, kD, ZD);
}